// Round 1
// baseline (13385.312 us; speedup 1.0000x reference)
//
#include <hip/hip_runtime.h>

// LSTM: L=2, B=64, T=512, H=1024
#define BB 64
#define TT 512
#define HH 1024
#define NL 2
#define G4 4096   // 4H
#define D2 2048   // 2H
#define TC 64     // timestep chunk for Gx buffer
#define NCHUNK (TT / TC)

typedef __attribute__((ext_vector_type(8))) short bf16x8;
typedef __attribute__((ext_vector_type(4))) float f32x4;

__device__ inline unsigned short f2bf(float f) {
  union { float f; unsigned u; } v; v.f = f;
  unsigned r = v.u + 0x7FFFu + ((v.u >> 16) & 1u);
  return (unsigned short)(r >> 16);
}

// ---------------- fp32 -> bf16 bulk convert (vectorized) ----------------
__global__ __launch_bounds__(256) void k_cvt(const float* __restrict__ src,
                                             unsigned short* __restrict__ dst, int n4) {
  int i = blockIdx.x * blockDim.x + threadIdx.x;
  int stride = gridDim.x * blockDim.x;
  for (; i < n4; i += stride) {
    float4 v = ((const float4*)src)[i];
    ushort4 o;
    o.x = f2bf(v.x); o.y = f2bf(v.y); o.z = f2bf(v.z); o.w = f2bf(v.w);
    ((ushort4*)dst)[i] = o;
  }
}

// bperm[l][nn] = bias[l][ (nn&3)*H + (nn>>2) ]   (interleaved gate order)
__global__ void k_biasperm(const float* __restrict__ b_in, float* __restrict__ bperm) {
  int i = blockIdx.x * blockDim.x + threadIdx.x;
  if (i < NL * G4) {
    int l = i >> 12, nn = i & 4095;
    bperm[i] = b_in[l * G4 + (nn & 3) * HH + (nn >> 2)];
  }
}

__global__ void k_init(const float* __restrict__ h0, const float* __restrict__ c0,
                       unsigned short* __restrict__ hbf0, float* __restrict__ cst, int l) {
  int i = blockIdx.x * blockDim.x + threadIdx.x;
  if (i < BB * HH) {
    hbf0[i] = f2bf(h0[l * BB * HH + i]);
    cst[i] = c0[l * BB * HH + i];
  }
}

// ---------------- x-projection GEMM ----------------
// Gx[tc][b][nn] = sum_k xbf[b][t0+tc][k] * W[perm(nn)][k] + bias[perm(nn)]
// M = TC*B = 4096 rows (m = tc*64 + b), N = 4096 (nn, interleaved), K = 1024.
// 128x128 tile, BK=64, 4 waves (2x2), global_load_lds staging with
// XOR swizzle (16B granule, slot ^= row&7) pre-applied on the SOURCE address.
__global__ __launch_bounds__(256) void k_xgemm(const unsigned short* __restrict__ xbf,
                                               const unsigned short* __restrict__ wbf,
                                               const float* __restrict__ bperm,
                                               float* __restrict__ gx,
                                               int layer, int t0) {
  __shared__ short lds[2 * 8192];  // A: 128x64 bf16 (16KB), B: same
  short* Ald = lds;
  short* Bld = lds + 8192;
  const int tid = threadIdx.x;
  const int lane = tid & 63;
  const int w = tid >> 6;
  const int bx = blockIdx.x, by = blockIdx.y;
  const unsigned short* wb = wbf + (size_t)layer * G4 * D2;

  f32x4 acc[4][4] = {};
  const int pslot = lane & 7;

  for (int kc = 0; kc < 16; ++kc) {
    __syncthreads();
    const int k0 = kc * 64;
#pragma unroll
    for (int i = 0; i < 4; ++i) {
      int r = (w * 4 + i) * 8 + (lane >> 3);     // tile row 0..127
      int lslot = pslot ^ (r & 7);               // logical 16B slot in row
      {  // A tile: row r -> (tc = mg>>6, b = mg&63)
        int mg = by * 128 + r;
        int b = mg & 63, t = t0 + (mg >> 6);
        const unsigned short* src = xbf + ((size_t)(b * TT + t)) * HH + k0 + lslot * 8;
        __builtin_amdgcn_global_load_lds((const __attribute__((address_space(1))) void*)src,
                                         (__attribute__((address_space(3))) void*)(Ald + (w * 4 + i) * 512),
                                         16, 0, 0);
      }
      {  // B tile: row r -> W row perm(ng)
        int ng = bx * 128 + r;
        int wrow = (ng & 3) * HH + (ng >> 2);
        const unsigned short* src = wb + (size_t)wrow * D2 + k0 + lslot * 8;
        __builtin_amdgcn_global_load_lds((const __attribute__((address_space(1))) void*)src,
                                         (__attribute__((address_space(3))) void*)(Bld + (w * 4 + i) * 512),
                                         16, 0, 0);
      }
    }
    asm volatile("s_waitcnt vmcnt(0)" ::: "memory");
    __syncthreads();

#pragma unroll
    for (int kk = 0; kk < 2; ++kk) {
      bf16x8 afr[4], bfr[4];
      int ls = kk * 4 + (lane >> 4);
#pragma unroll
      for (int f = 0; f < 4; ++f) {
        int ra = (w >> 1) * 64 + f * 16 + (lane & 15);
        int ps = ls ^ (ra & 7);
        afr[f] = *(const bf16x8*)((const char*)Ald + ra * 128 + ps * 16);
        int rb = (w & 1) * 64 + f * 16 + (lane & 15);
        int psb = ls ^ (rb & 7);
        bfr[f] = *(const bf16x8*)((const char*)Bld + rb * 128 + psb * 16);
      }
#pragma unroll
      for (int fi = 0; fi < 4; ++fi)
#pragma unroll
        for (int fj = 0; fj < 4; ++fj)
          acc[fi][fj] = __builtin_amdgcn_mfma_f32_16x16x32_bf16(afr[fi], bfr[fj], acc[fi][fj], 0, 0, 0);
    }
  }

  const float* bp = bperm + layer * G4;
#pragma unroll
  for (int fj = 0; fj < 4; ++fj) {
    int col = bx * 128 + (w & 1) * 64 + fj * 16 + (lane & 15);
    float bv = bp[col];
#pragma unroll
    for (int fi = 0; fi < 4; ++fi) {
      int mg = by * 128 + (w >> 1) * 64 + fi * 16 + (lane >> 4) * 4;
#pragma unroll
      for (int r = 0; r < 4; ++r)
        gx[(size_t)(mg + r) * G4 + col] = acc[fi][fj][r] + bv;
    }
  }
}

// ---------------- recurrent step ----------------
// One WG per 16 interleaved gate-columns (4 hidden units x 4 gates).
// 4 waves, wave w handles batches [16w, 16w+16). K=1024 over Wh.
// Fused elementwise LSTM update via LDS gate exchange.
__global__ __launch_bounds__(256) void k_step(const unsigned short* __restrict__ hbf_in,
                                              unsigned short* __restrict__ hbf_out,
                                              const unsigned short* __restrict__ wbf,
                                              const float* __restrict__ gx,
                                              float* __restrict__ cst,
                                              float* __restrict__ dout,
                                              unsigned short* __restrict__ xnext,
                                              int layer, int t, int tt) {
  __shared__ float gl[64 * 20];
  const int tid = threadIdx.x;
  const int lane = tid & 63;
  const int w = tid >> 6;
  const int wg = blockIdx.x;
  const unsigned short* wb = wbf + (size_t)layer * G4 * D2;

  const int ng = wg * 16 + (lane & 15);
  const unsigned short* wsrc = wb + (size_t)((ng & 3) * HH + (ng >> 2)) * D2 + HH + (lane >> 4) * 8;
  const unsigned short* asrc = hbf_in + (size_t)(w * 16 + (lane & 15)) * HH + (lane >> 4) * 8;

  f32x4 acc = {0.f, 0.f, 0.f, 0.f};
#pragma unroll 8
  for (int ks = 0; ks < 32; ++ks) {
    bf16x8 a = *(const bf16x8*)(asrc + ks * 32);
    bf16x8 b = *(const bf16x8*)(wsrc + ks * 32);
    acc = __builtin_amdgcn_mfma_f32_16x16x32_bf16(a, b, acc, 0, 0, 0);
  }

  {
    int row = w * 16 + (lane >> 4) * 4;
    int col = lane & 15;
#pragma unroll
    for (int r = 0; r < 4; ++r) gl[(row + r) * 20 + col] = acc[r];
  }
  __syncthreads();

  {
    int b = tid >> 2, j = tid & 3;
    int u = wg * 4 + j;
    float f = gl[b * 20 + j * 4 + 0];
    float i = gl[b * 20 + j * 4 + 1];
    float g = gl[b * 20 + j * 4 + 2];
    float o = gl[b * 20 + j * 4 + 3];
    const float4 gx4 = *(const float4*)(gx + ((size_t)(tt * BB + b)) * G4 + u * 4);
    f += gx4.x; i += gx4.y; g += gx4.z; o += gx4.w;
    float c_old = cst[b * HH + u];
    float sf = 1.0f / (1.0f + expf(-f));
    float si = 1.0f / (1.0f + expf(-i));
    float so = 1.0f / (1.0f + expf(-o));
    float cn = sf * c_old + si * tanhf(g);
    float hn = so * tanhf(cn);
    cst[b * HH + u] = cn;
    unsigned short hb = f2bf(hn);
    hbf_out[b * HH + u] = hb;
    dout[((size_t)b * TT + t) * HH + u] = hn;
    if (xnext) xnext[((size_t)b * TT + t) * HH + u] = hb;
  }
}

// h_n[l] = out[:, T-1, :], c_n[l] = c_state
__global__ void k_finals(const float* __restrict__ cst, float* __restrict__ dout, int layer) {
  int i = blockIdx.x * blockDim.x + threadIdx.x;
  if (i < BB * HH) {
    int b = i >> 10, u = i & 1023;
    dout[(size_t)BB * TT * HH + (size_t)layer * BB * HH + i] =
        dout[((size_t)b * TT + (TT - 1)) * HH + u];
    dout[(size_t)BB * TT * HH + (size_t)NL * BB * HH + (size_t)layer * BB * HH + i] = cst[i];
  }
}

extern "C" void kernel_launch(void* const* d_in, const int* in_sizes, int n_in,
                              void* d_out, int out_size, void* d_ws, size_t ws_size,
                              hipStream_t stream) {
  const float* x = (const float*)d_in[0];
  const float* W = (const float*)d_in[1];
  const float* bias = (const float*)d_in[2];
  const float* h0 = (const float*)d_in[3];
  const float* c0 = (const float*)d_in[4];
  float* out = (float*)d_out;

  char* ws = (char*)d_ws;
  unsigned short* wbf = (unsigned short*)(ws + 0);            // 33,554,432 B
  unsigned short* xbf = (unsigned short*)(ws + 33554432);     // 67,108,864 B
  float* gx = (float*)(ws + 100663296);                       // 67,108,864 B
  unsigned short* hbf = (unsigned short*)(ws + 167772160);    // 262,144 B (2 x B*H bf16)
  float* cst = (float*)(ws + 168034304);                      // 262,144 B
  float* bperm = (float*)(ws + 168296448);                    // 32,768 B
  // total ws use: 168,329,216 B

  k_cvt<<<2048, 256, 0, stream>>>(W, wbf, NL * G4 * D2 / 4);
  k_cvt<<<2048, 256, 0, stream>>>(x, xbf, BB * TT * HH / 4);
  k_biasperm<<<(NL * G4 + 255) / 256, 256, 0, stream>>>(bias, bperm);

  for (int l = 0; l < NL; ++l) {
    k_init<<<BB * HH / 256, 256, 0, stream>>>(h0, c0, hbf, cst, l);
    for (int c = 0; c < NCHUNK; ++c) {
      k_xgemm<<<dim3(32, 32), 256, 0, stream>>>(xbf, wbf, bperm, gx, l, c * TC);
      for (int tt = 0; tt < TC; ++tt) {
        int t = c * TC + tt;
        const unsigned short* hin = hbf + (size_t)(t & 1) * BB * HH;
        unsigned short* hout = hbf + (size_t)((t + 1) & 1) * BB * HH;
        k_step<<<256, 256, 0, stream>>>(hin, hout, wbf, gx, cst, out,
                                        (l == 0) ? xbf : (unsigned short*)nullptr, l, t, tt);
      }
    }
    k_finals<<<256, 256, 0, stream>>>(cst, out, l);
  }
}